// Round 1
// baseline (605.484 us; speedup 1.0000x reference)
//
#include <hip/hip_runtime.h>
#include <hip/hip_bf16.h>
#include <cstdint>
#include <cstddef>

// Problem constants (from reference): X[S,B,D], W[3H,D], S=2048 B=16 D=1024 H=1024
#define S_LEN 2048
#define BATCH 16
#define DIM   1024
#define HID   1024
#define M_TOT (S_LEN * BATCH)   // 32768
#define N_TOT (3 * HID)         // 3072
#define K_TOT DIM               // 1024
#define NCHUNK 32
#define CHLEN (S_LEN / NCHUNK)  // 64

typedef __bf16 bf16x8 __attribute__((ext_vector_type(8)));
typedef float  f32x4  __attribute__((ext_vector_type(4)));

__device__ __forceinline__ unsigned short f2bf(float f) {
    unsigned int u = __float_as_uint(f);
    u += 0x7FFFu + ((u >> 16) & 1u);   // round-to-nearest-even
    return (unsigned short)(u >> 16);
}
__device__ __forceinline__ float bf2f(unsigned short s) {
    return __uint_as_float(((unsigned int)s) << 16);
}

template <typename GT> __device__ __forceinline__ float ld_gate(const GT* p, int i);
template <> __device__ __forceinline__ float ld_gate<float>(const float* p, int i) { return p[i]; }
template <> __device__ __forceinline__ float ld_gate<unsigned short>(const unsigned short* p, int i) { return bf2f(p[i]); }

template <typename GT> __device__ __forceinline__ void st_gate(GT* p, int i, float v);
template <> __device__ __forceinline__ void st_gate<float>(float* p, int i, float v) { p[i] = v; }
template <> __device__ __forceinline__ void st_gate<unsigned short>(unsigned short* p, int i, float v) { p[i] = f2bf(v); }

__device__ __forceinline__ float fast_sigmoid(float x) { return 1.0f / (1.0f + __expf(-x)); }
__device__ __forceinline__ float fast_tanh(float x)    { return 2.0f / (1.0f + __expf(-2.0f * x)) - 1.0f; }

// ---------------- fp32 -> bf16 conversion (X and W) ----------------
__global__ void __launch_bounds__(256) cvt_f32_bf16(const float* __restrict__ in,
                                                    unsigned short* __restrict__ out, int n4) {
    int i = blockIdx.x * blockDim.x + threadIdx.x;
    const int stride = gridDim.x * blockDim.x;
    for (; i < n4; i += stride) {
        const float4 v = reinterpret_cast<const float4*>(in)[i];
        ushort4 o;
        o.x = f2bf(v.x); o.y = f2bf(v.y); o.z = f2bf(v.z); o.w = f2bf(v.w);
        reinterpret_cast<ushort4*>(out)[i] = o;
    }
}

// ---------------- GEMM: gates = act(X * W^T + b) ----------------
// A = Xb [M,K] row-major bf16; B^T = Wb [N,K] row-major bf16 (W is [3H,D] = [N,K]).
// 128x128 tile, BK=64, 4 waves (2x2), 16x16x32 bf16 MFMA, global_load_lds staging.
#define GLOAD_LDS16(gp, lp)                                                         \
    __builtin_amdgcn_global_load_lds((__attribute__((address_space(1))) void*)(gp), \
                                     (__attribute__((address_space(3))) void*)(lp), 16, 0, 0)

template <typename GT>
__global__ void __launch_bounds__(256) gemm_gates(const unsigned short* __restrict__ Xb,
                                                  const unsigned short* __restrict__ Wb,
                                                  const float* __restrict__ bias,
                                                  GT* __restrict__ gates) {
    __shared__ unsigned short As[128 * 64];
    __shared__ unsigned short Bs[128 * 64];
    const int t    = threadIdx.x;
    const int bn   = blockIdx.x;   // 0..23  (N tiles)
    const int bm   = blockIdx.y;   // 0..255 (M tiles)
    const int lane = t & 63;
    const int wid  = t >> 6;
    const int wm   = wid >> 1;     // 0..1
    const int wn   = wid & 1;      // 0..1
    const int lr   = lane & 15;
    const int lk   = (lane >> 4) << 3;   // k offset 0/8/16/24

    // staging: each thread moves 16B (8 bf16); 256 threads cover 32 rows x 64 cols per issue
    const int srow = t >> 3;             // 0..31
    const int scol = (t & 7) << 3;       // 0..56
    const unsigned short* gA = Xb + (size_t)(bm * 128 + srow) * K_TOT + scol;
    const unsigned short* gB = Wb + (size_t)(bn * 128 + srow) * K_TOT + scol;
    unsigned short* lA = &As[srow * 64 + scol];
    unsigned short* lB = &Bs[srow * 64 + scol];

    f32x4 acc[4][4];
#pragma unroll
    for (int m = 0; m < 4; ++m)
#pragma unroll
        for (int n = 0; n < 4; ++n) acc[m][n] = {0.0f, 0.0f, 0.0f, 0.0f};

    for (int k0 = 0; k0 < K_TOT; k0 += 64) {
#pragma unroll
        for (int i = 0; i < 4; ++i) {
            GLOAD_LDS16(gA + (size_t)i * 32 * K_TOT + k0, lA + i * 32 * 64);
            GLOAD_LDS16(gB + (size_t)i * 32 * K_TOT + k0, lB + i * 32 * 64);
        }
        __syncthreads();   // drains vmcnt(0): staged tile visible
#pragma unroll
        for (int kk = 0; kk < 2; ++kk) {
            bf16x8 av[4], bv[4];
#pragma unroll
            for (int m = 0; m < 4; ++m)
                av[m] = *reinterpret_cast<const bf16x8*>(&As[(wm * 64 + m * 16 + lr) * 64 + kk * 32 + lk]);
#pragma unroll
            for (int n = 0; n < 4; ++n)
                bv[n] = *reinterpret_cast<const bf16x8*>(&Bs[(wn * 64 + n * 16 + lr) * 64 + kk * 32 + lk]);
#pragma unroll
            for (int m = 0; m < 4; ++m)
#pragma unroll
                for (int n = 0; n < 4; ++n)
                    acc[m][n] = __builtin_amdgcn_mfma_f32_16x16x32_bf16(av[m], bv[n], acc[m][n], 0, 0, 0);
        }
        __syncthreads();   // protect LDS before next stage
    }

    // Epilogue: bias + activation. C/D layout: col = lane&15, row = (lane>>4)*4 + reg.
    const int gate_id = bn >> 3;  // 0: tanh(Z), 1: sigmoid(F), 2: sigmoid(O) — uniform per block
    const int r0 = bm * 128 + wm * 64 + ((lane >> 4) << 2);
    const int c0 = bn * 128 + wn * 64 + lr;
#pragma unroll
    for (int n = 0; n < 4; ++n) {
        const int col = c0 + n * 16;
        const float bb = bias[col];
#pragma unroll
        for (int m = 0; m < 4; ++m) {
            const int row = r0 + m * 16;
#pragma unroll
            for (int r = 0; r < 4; ++r) {
                const float y = acc[m][n][r] + bb;
                const float g = (gate_id == 0) ? fast_tanh(y) : fast_sigmoid(y);
                st_gate(gates, (row + r) * N_TOT + col, g);
            }
        }
    }
}

// ---------------- chunked linear scan (fo-pool) ----------------
// Phase 1: per (chunk, b, h): local scan from 0, track a = prod(1-f).
template <typename GT>
__global__ void __launch_bounds__(256) scan_phase1(const GT* __restrict__ gates,
                                                   float* __restrict__ Aprod,
                                                   float* __restrict__ Cend) {
    const int t = blockIdx.x * 256 + threadIdx.x;  // 0..524287 = chunk*16384 + b*1024 + h
    const int h = t & (HID - 1);
    const int b = (t >> 10) & (BATCH - 1);
    const int chunk = t >> 14;
    float c = 0.0f, a = 1.0f;
    const int m0 = chunk * (CHLEN * BATCH) + b;
#pragma unroll 4
    for (int i = 0; i < CHLEN; ++i) {
        const int base = (m0 + i * BATCH) * N_TOT;
        const float z = ld_gate(gates, base + h);
        const float f = ld_gate(gates, base + HID + h);
        const float omf = 1.0f - f;
        c = f * z + omf * c;
        a *= omf;
    }
    Aprod[t] = a;
    Cend[t] = c;
}

// Phase 2: per channel, combine the 32 chunk summaries sequentially.
__global__ void __launch_bounds__(256) scan_combine(const float* __restrict__ Aprod,
                                                    const float* __restrict__ Cend,
                                                    const float* __restrict__ hidden,
                                                    float* __restrict__ Cstart,
                                                    float* __restrict__ c_last) {
    const int t = blockIdx.x * 256 + threadIdx.x;  // 0..16383 = b*1024 + h
    float c = hidden[t];
#pragma unroll
    for (int j = 0; j < NCHUNK; ++j) {
        const int idx = j * (BATCH * HID) + t;
        Cstart[idx] = c;
        c = Aprod[idx] * c + Cend[idx];
    }
    c_last[t] = c;   // C[-1]
}

// Phase 3: re-run local scan with the correct start, emit H = O * C.
template <typename GT>
__global__ void __launch_bounds__(256) scan_phase3(const GT* __restrict__ gates,
                                                   const float* __restrict__ Cstart,
                                                   float* __restrict__ Hout) {
    const int t = blockIdx.x * 256 + threadIdx.x;
    const int h = t & (HID - 1);
    const int b = (t >> 10) & (BATCH - 1);
    const int chunk = t >> 14;
    float c = Cstart[t];
    const int m0 = chunk * (CHLEN * BATCH) + b;
#pragma unroll 4
    for (int i = 0; i < CHLEN; ++i) {
        const int m = m0 + i * BATCH;
        const int base = m * N_TOT;
        const float z = ld_gate(gates, base + h);
        const float f = ld_gate(gates, base + HID + h);
        const float o = ld_gate(gates, base + 2 * HID + h);
        c = f * z + (1.0f - f) * c;
        Hout[m * HID + h] = o * c;
    }
}

// ---------------- launch ----------------
extern "C" void kernel_launch(void* const* d_in, const int* in_sizes, int n_in,
                              void* d_out, int out_size, void* d_ws, size_t ws_size,
                              hipStream_t stream) {
    const float* X      = (const float*)d_in[0];
    const float* hidden = (const float*)d_in[1];
    const float* W      = (const float*)d_in[2];
    const float* bias   = (const float*)d_in[3];
    float* out    = (float*)d_out;
    float* c_last = out + (size_t)M_TOT * HID;   // outputs concatenated: H_out then C[-1:]

    char* ws = (char*)d_ws;
    unsigned short* Xb = (unsigned short*)ws;                               // 64 MiB
    unsigned short* Wb = (unsigned short*)(ws + (size_t)M_TOT * K_TOT * 2); // 6 MiB
    char* after_w = ws + (size_t)M_TOT * K_TOT * 2 + (size_t)N_TOT * K_TOT * 2;

    const size_t n_gate    = (size_t)M_TOT * N_TOT;          // 100,663,296
    const size_t sum_elems = (size_t)NCHUNK * BATCH * HID;   // 524,288
    const size_t need_f32  = (size_t)(after_w - ws) + n_gate * 4 + sum_elems * 12;

    cvt_f32_bf16<<<dim3(2048), dim3(256), 0, stream>>>(X, Xb, (int)(M_TOT * K_TOT / 4));
    cvt_f32_bf16<<<dim3(512),  dim3(256), 0, stream>>>(W, Wb, (int)(N_TOT * K_TOT / 4));

    if (ws_size >= need_f32) {
        float* gates  = (float*)after_w;
        float* Aprod  = gates + n_gate;
        float* Cend   = Aprod + sum_elems;
        float* Cstart = Cend + sum_elems;
        gemm_gates<float><<<dim3(24, 256), dim3(256), 0, stream>>>(Xb, Wb, bias, gates);
        scan_phase1<float><<<dim3(2048), dim3(256), 0, stream>>>(gates, Aprod, Cend);
        scan_combine<<<dim3(64), dim3(256), 0, stream>>>(Aprod, Cend, hidden, Cstart, c_last);
        scan_phase3<float><<<dim3(2048), dim3(256), 0, stream>>>(gates, Cstart, out);
    } else {
        unsigned short* gates = (unsigned short*)after_w;
        float* Aprod  = (float*)(after_w + n_gate * 2);
        float* Cend   = Aprod + sum_elems;
        float* Cstart = Cend + sum_elems;
        gemm_gates<unsigned short><<<dim3(24, 256), dim3(256), 0, stream>>>(Xb, Wb, bias, gates);
        scan_phase1<unsigned short><<<dim3(2048), dim3(256), 0, stream>>>(gates, Aprod, Cend);
        scan_combine<<<dim3(64), dim3(256), 0, stream>>>(Aprod, Cend, hidden, Cstart, c_last);
        scan_phase3<unsigned short><<<dim3(2048), dim3(256), 0, stream>>>(gates, Cstart, out);
    }
}

// Round 2
// 442.199 us; speedup vs baseline: 1.3693x; 1.3693x over previous
//
#include <hip/hip_runtime.h>
#include <hip/hip_bf16.h>
#include <cstdint>
#include <cstddef>

// Problem constants: X[S,B,D], W[3H,D], S=2048 B=16 D=1024 H=1024
#define S_LEN 2048
#define BATCH 16
#define DIM   1024
#define HID   1024
#define M_TOT (S_LEN * BATCH)   // 32768
#define N_TOT (3 * HID)         // 3072
#define K_TOT DIM               // 1024
#define NCHUNK 32
#define CHLEN (S_LEN / NCHUNK)  // 64

// GEMM geometry
#define BM 256
#define BN 256
#define BK 32
#define NT (K_TOT / BK)          // 32 K-tiles
#define GRID_M (M_TOT / BM)      // 128
#define GRID_N (N_TOT / BN)      // 12
#define NWG (GRID_M * GRID_N)    // 1536 (divisible by 8 -> simple XCD swizzle valid)

typedef __bf16 bf16x8 __attribute__((ext_vector_type(8)));
typedef float  f32x4  __attribute__((ext_vector_type(4)));

__device__ __forceinline__ unsigned short f2bf(float f) {
    unsigned int u = __float_as_uint(f);
    u += 0x7FFFu + ((u >> 16) & 1u);   // RNE
    return (unsigned short)(u >> 16);
}
__device__ __forceinline__ float bf2f(unsigned int s) {
    return __uint_as_float(s << 16);
}
__device__ __forceinline__ float fast_sigmoid(float x) { return 1.0f / (1.0f + __expf(-x)); }
__device__ __forceinline__ float fast_tanh(float x)    { return 2.0f / (1.0f + __expf(-2.0f * x)) - 1.0f; }

// ---------------- fp32 -> bf16 conversion (X and W) ----------------
__global__ void __launch_bounds__(256) cvt_f32_bf16(const float* __restrict__ in,
                                                    unsigned short* __restrict__ out, int n4) {
    int i = blockIdx.x * blockDim.x + threadIdx.x;
    const int stride = gridDim.x * blockDim.x;
    for (; i < n4; i += stride) {
        const float4 v = reinterpret_cast<const float4*>(in)[i];
        ushort4 o;
        o.x = f2bf(v.x); o.y = f2bf(v.y); o.z = f2bf(v.z); o.w = f2bf(v.w);
        reinterpret_cast<ushort4*>(out)[i] = o;
    }
}

// ---------------- GEMM: gates = act(X * W^T + b), bf16 out ----------------
// 256x256 tile, BK=32, 8 waves (2Mx4N), 4-slot LDS ring, counted vmcnt(8),
// XOR-swizzled LDS (chunk ^= (row>>1)&3, 16B granules) staged via pre-swizzled
// global source (global_load_lds writes linearly: rule #21).
#define GLOAD_LDS16(gp, lp)                                                         \
    __builtin_amdgcn_global_load_lds((__attribute__((address_space(1))) void*)(gp), \
                                     (__attribute__((address_space(3))) void*)(lp), 16, 0, 0)

__global__ void __launch_bounds__(512, 2)
gemm_gates(const unsigned short* __restrict__ Xb,
           const unsigned short* __restrict__ Wb,
           const float* __restrict__ bias,
           unsigned short* __restrict__ gates) {
    __shared__ unsigned short As[4][BM * BK];   // 4 x 16 KiB
    __shared__ unsigned short Bs[4][BN * BK];   // 4 x 16 KiB  (128 KiB total)

    const int tid  = threadIdx.x;
    const int lane = tid & 63;
    const int wid  = tid >> 6;     // 0..7
    const int wm   = wid >> 2;     // 0..1  (wave output: 128x64 at (wm*128, wn*64))
    const int wn   = wid & 3;      // 0..3
    const int lr   = lane & 15;
    const int lc   = lane >> 4;    // k-chunk 0..3 (8 elems each)

    // XCD-aware bijective swizzle; bn-fastest within chunk -> A-panels L2-resident
    const int swz = (blockIdx.x & 7) * (NWG / 8) + (blockIdx.x >> 3);
    const int bn = swz % GRID_N;
    const int bm = swz / GRID_N;

    // Staging: per K-tile, A = 256x32 bf16 = 16KB = 2 issues x 512 thr x 16B. Same for B.
    // Physical LDS byte P = i*8192 + tid*16 (linear, wave-uniform base + lane*16).
    // Logical (row, colElem): row = P>>6; colElem = ((P&63)>>1) ^ (((row>>1)&3)<<3).
    const int srow  = tid >> 2;                                  // issue-0 row (0..127)
    const int scolE = (((tid & 3) ^ ((tid >> 3) & 3)) << 3);     // pre-swizzled k-col
    const unsigned short* gA = Xb + (size_t)(bm * BM + srow) * K_TOT + scolE;
    const unsigned short* gB = Wb + (size_t)(bn * BN + srow) * K_TOT + scolE;
    unsigned short* lA = &As[0][tid * 8];   // tid*16 bytes
    unsigned short* lB = &Bs[0][tid * 8];

#define STAGE(tt) do {                                                   \
        const int _s = (tt) & 3; const int _k = (tt) * BK;               \
        GLOAD_LDS16(gA + _k,                lA + _s * (BM * BK));        \
        GLOAD_LDS16(gA + 128 * K_TOT + _k,  lA + _s * (BM * BK) + 4096); \
        GLOAD_LDS16(gB + _k,                lB + _s * (BN * BK));        \
        GLOAD_LDS16(gB + 128 * K_TOT + _k,  lB + _s * (BN * BK) + 4096); \
    } while (0)

    f32x4 acc[8][4];
#pragma unroll
    for (int m = 0; m < 8; ++m)
#pragma unroll
        for (int n = 0; n < 4; ++n) acc[m][n] = {0.0f, 0.0f, 0.0f, 0.0f};

    // Prologue: stage tiles 0,1,2; wait for tile 0 (12 outstanding -> 8)
    STAGE(0); STAGE(1); STAGE(2);
    asm volatile("s_waitcnt vmcnt(8)" ::: "memory");
    __builtin_amdgcn_s_barrier();

    for (int t = 0; t < NT; ++t) {
        const int s = t & 3;
        // Fragment ds_reads (swizzled): 8 A + 4 B ds_read_b128, conflict-free
        bf16x8 av[8], bv[4];
#pragma unroll
        for (int m = 0; m < 8; ++m) {
            const int row = wm * 128 + m * 16 + lr;
            av[m] = *reinterpret_cast<const bf16x8*>(
                &As[s][row * BK + ((lc ^ ((row >> 1) & 3)) << 3)]);
        }
#pragma unroll
        for (int n = 0; n < 4; ++n) {
            const int row = wn * 64 + n * 16 + lr;
            bv[n] = *reinterpret_cast<const bf16x8*>(
                &Bs[s][row * BK + ((lc ^ ((row >> 1) & 3)) << 3)]);
        }
        // Prefetch tile t+3 (slot free since t-1's reads completed before t began)
        if (t + 3 < NT) {
            STAGE(t + 3);
            asm volatile("s_waitcnt vmcnt(8)" ::: "memory");   // waits only tile t+1's 4 loads
        } else if (t + 3 == NT) {
            asm volatile("s_waitcnt vmcnt(4)" ::: "memory");
        } else if (t + 2 == NT) {
            asm volatile("s_waitcnt vmcnt(0)" ::: "memory");
        }
        __builtin_amdgcn_s_barrier();
        __builtin_amdgcn_s_setprio(1);
#pragma unroll
        for (int m = 0; m < 8; ++m)
#pragma unroll
            for (int n = 0; n < 4; ++n)
                acc[m][n] = __builtin_amdgcn_mfma_f32_16x16x32_bf16(av[m], bv[n], acc[m][n], 0, 0, 0);
        __builtin_amdgcn_s_setprio(0);
        __builtin_amdgcn_s_barrier();
    }
#undef STAGE

    // Epilogue: bias + activation, bf16 store. C/D: col=lane&15, row=(lane>>4)*4+reg.
    const int gate_id = bn >> 2;  // 0:tanh(Z) 1:sig(F) 2:sig(O), uniform per block
    const int c0 = bn * BN + wn * 64 + lr;
    const int r0 = bm * BM + wm * 128 + ((lane >> 4) << 2);
#pragma unroll
    for (int n = 0; n < 4; ++n) {
        const int col = c0 + n * 16;
        const float bb = bias[col];
#pragma unroll
        for (int m = 0; m < 8; ++m) {
            const int rowb = r0 + m * 16;
#pragma unroll
            for (int r = 0; r < 4; ++r) {
                const float y = acc[m][n][r] + bb;
                const float g = (gate_id == 0) ? fast_tanh(y) : fast_sigmoid(y);
                gates[(size_t)(rowb + r) * N_TOT + col] = f2bf(g);
            }
        }
    }
}

// ---------------- chunked linear scan (fo-pool), vec2 over h ----------------
// Phase 1: per (chunk,b,hpair): local scan from 0, track a = prod(1-f).
__global__ void __launch_bounds__(256) scan_phase1(const unsigned short* __restrict__ gates,
                                                   float* __restrict__ Aprod,
                                                   float* __restrict__ Cend) {
    const int t = blockIdx.x * 256 + threadIdx.x;  // 0..262143 = chunk*8192 + b*512 + hp
    const int hp = t & 511;
    const int b  = (t >> 9) & (BATCH - 1);
    const int chunk = t >> 13;
    float c0 = 0.f, c1 = 0.f, a0 = 1.f, a1 = 1.f;
    const int m0 = chunk * (CHLEN * BATCH) + b;
    const unsigned short* gz = gates + (size_t)m0 * N_TOT + hp * 2;
#pragma unroll 4
    for (int i = 0; i < CHLEN; ++i) {
        const unsigned short* p = gz + (size_t)i * BATCH * N_TOT;
        const unsigned int zz = *reinterpret_cast<const unsigned int*>(p);
        const unsigned int ff = *reinterpret_cast<const unsigned int*>(p + HID);
        const float z0 = bf2f(zz & 0xffffu), z1 = bf2f(zz >> 16);
        const float f0 = bf2f(ff & 0xffffu), f1 = bf2f(ff >> 16);
        const float o0 = 1.f - f0, o1 = 1.f - f1;
        c0 = f0 * z0 + o0 * c0;  c1 = f1 * z1 + o1 * c1;
        a0 *= o0;                a1 *= o1;
    }
    const int idx = chunk * (BATCH * HID) + b * HID + hp * 2;
    *reinterpret_cast<float2*>(&Aprod[idx]) = make_float2(a0, a1);
    *reinterpret_cast<float2*>(&Cend[idx])  = make_float2(c0, c1);
}

// Phase 2: per channel, combine the 32 chunk summaries sequentially.
__global__ void __launch_bounds__(256) scan_combine(const float* __restrict__ Aprod,
                                                    const float* __restrict__ Cend,
                                                    const float* __restrict__ hidden,
                                                    float* __restrict__ Cstart,
                                                    float* __restrict__ c_last) {
    const int t = blockIdx.x * 256 + threadIdx.x;  // 0..16383 = b*1024 + h
    float c = hidden[t];
#pragma unroll
    for (int j = 0; j < NCHUNK; ++j) {
        const int idx = j * (BATCH * HID) + t;
        Cstart[idx] = c;
        c = Aprod[idx] * c + Cend[idx];
    }
    c_last[t] = c;
}

// Phase 3: re-run local scan with correct start, emit H = O * C (fp32 out).
__global__ void __launch_bounds__(256) scan_phase3(const unsigned short* __restrict__ gates,
                                                   const float* __restrict__ Cstart,
                                                   float* __restrict__ Hout) {
    const int t = blockIdx.x * 256 + threadIdx.x;
    const int hp = t & 511;
    const int b  = (t >> 9) & (BATCH - 1);
    const int chunk = t >> 13;
    const int idx = chunk * (BATCH * HID) + b * HID + hp * 2;
    float2 cs = *reinterpret_cast<const float2*>(&Cstart[idx]);
    float c0 = cs.x, c1 = cs.y;
    const int m0 = chunk * (CHLEN * BATCH) + b;
    const unsigned short* gz = gates + (size_t)m0 * N_TOT + hp * 2;
#pragma unroll 4
    for (int i = 0; i < CHLEN; ++i) {
        const unsigned short* p = gz + (size_t)i * BATCH * N_TOT;
        const unsigned int zz = *reinterpret_cast<const unsigned int*>(p);
        const unsigned int ff = *reinterpret_cast<const unsigned int*>(p + HID);
        const unsigned int oo = *reinterpret_cast<const unsigned int*>(p + 2 * HID);
        const float z0 = bf2f(zz & 0xffffu), z1 = bf2f(zz >> 16);
        const float f0 = bf2f(ff & 0xffffu), f1 = bf2f(ff >> 16);
        const float g0 = bf2f(oo & 0xffffu), g1 = bf2f(oo >> 16);
        c0 = f0 * z0 + (1.f - f0) * c0;
        c1 = f1 * z1 + (1.f - f1) * c1;
        const int m = m0 + i * BATCH;
        *reinterpret_cast<float2*>(&Hout[(size_t)m * HID + hp * 2]) = make_float2(g0 * c0, g1 * c1);
    }
}

// ---------------- launch ----------------
extern "C" void kernel_launch(void* const* d_in, const int* in_sizes, int n_in,
                              void* d_out, int out_size, void* d_ws, size_t ws_size,
                              hipStream_t stream) {
    const float* X      = (const float*)d_in[0];
    const float* hidden = (const float*)d_in[1];
    const float* W      = (const float*)d_in[2];
    const float* bias   = (const float*)d_in[3];
    float* out    = (float*)d_out;
    float* c_last = out + (size_t)M_TOT * HID;   // outputs: H_out then C[-1:]

    char* ws = (char*)d_ws;
    unsigned short* Xb    = (unsigned short*)ws;                                // 64 MiB
    unsigned short* Wb    = (unsigned short*)(ws + (size_t)M_TOT * K_TOT * 2);  // 6 MiB
    unsigned short* gates = Wb + (size_t)N_TOT * K_TOT;                         // 192 MiB bf16
    float* Aprod  = (float*)(gates + (size_t)M_TOT * N_TOT);
    float* Cend   = Aprod + (size_t)NCHUNK * BATCH * HID;
    float* Cstart = Cend  + (size_t)NCHUNK * BATCH * HID;

    cvt_f32_bf16<<<dim3(2048), dim3(256), 0, stream>>>(X, Xb, (int)(M_TOT * K_TOT / 4));
    cvt_f32_bf16<<<dim3(512),  dim3(256), 0, stream>>>(W, Wb, (int)(N_TOT * K_TOT / 4));
    gemm_gates<<<dim3(NWG), dim3(512), 0, stream>>>(Xb, Wb, bias, gates);
    scan_phase1<<<dim3(1024), dim3(256), 0, stream>>>(gates, Aprod, Cend);
    scan_combine<<<dim3(64), dim3(256), 0, stream>>>(Aprod, Cend, hidden, Cstart, c_last);
    scan_phase3<<<dim3(1024), dim3(256), 0, stream>>>(gates, Cstart, out);
}